// Round 11
// baseline (150.549 us; speedup 1.0000x reference)
//
#include <hip/hip_runtime.h>

// input_tensor: [8,128,128,128,1] fp32 ; random_u: [8,8,3] fp32 ; SCALE=0.2
#define NB   8
#define NS   128
#define VOX  (NS*NS*NS)

// R11: BARRIER-FREE PER-WAVE PIPELINE. R0-R10 ledger: time pinned 40-42 us
// across occupancy 16-40%, 4/8/16 vox/thread, while per-pipe work is VALU
// ~17 us, DS ~18 us, VMEM ~14 us -> wall == SUM of pipes, not max: the
// stage -> __syncthreads+vmcnt(0) -> compute chain phase-locks all resident
// blocks (convoy), so pipes never overlap across blocks. Fix: each WAVE
// stages its own clamped window into a PRIVATE LDS slice; no __syncthreads
// anywhere; wave-local counted s_waitcnt vmcnt(N) ladder (T4) overlaps its
// own staging with compute, and 10 self-paced waves/CU de-correlate phases.
// Per-wave window (kd<=7, dh<=1, kw<=31):
//   d: 7*1+0.1+3.1=10.2 -> floor span<=11 -> SD=13 planes
//   h: 0.7+1+3.1=4.8    -> floor span<=5  -> SHW=7 rows
//   w: 0.7+0.1+31=31.8  -> floor span<=32 -> <=34 cols +align4 -> ROW_W=40
// Slice = 13*7*40 = 3640 floats, staged as 15 x 256-float lane-linear loads
// (stride padded to 3840). Windows CLAMPED into the image => all 15 loads
// always valid & unconditional (vmcnt count exact); boundary waves (~55%)
// use masked-weight taps (R0-proven) after a single drain; interior waves
// run the per-k ladder: k needs planes <= 6+k -> loads <= ceil(280(6+k)/256)
// -> vmcnt = {8,7,6,5,4,2,1,0}.
#define SD      13
#define SHW     7
#define ROW_W   40
#define PLANE   (SHW*ROW_W)    // 280
#define WSLICE  3640           // floats actually used
#define WSTRIDE 3840           // 15*256, padded (last load + pair-read pad)
#define NLOAD   15

typedef __attribute__((address_space(1))) const void gconst_t;
typedef __attribute__((address_space(3))) void lds_t;

__global__ __launch_bounds__(128) void warp_resample_kernel(
        const float* __restrict__ img, const float* __restrict__ u,
        float* __restrict__ out) {
    __shared__ __align__(16) float slab[2 * WSTRIDE];   // 30,720 B -> 5 blk/CU

    const int tid  = threadIdx.x;
    const int wid  = tid >> 6;          // wave in block (0,1) — fully independent
    const int lane = tid & 63;
    // XCD pinning (R3/R7: FETCH 70->27 MB): b = bi&7
    const int bi   = blockIdx.x;
    const int b    =  bi & 7;
    const int idx  =  bi >> 3;
    const int wblk =  idx & 3;          // 4 w-tiles of 32
    const int hblk = (idx >> 2) & 31;   // 32 h-tiles of 4 (2 per wave)
    const int dblk =  idx >> 7;         // 16 d-tiles of 8

    // ---- transform: all lanes uniform (Walsh butterfly; 1/8 folded in) ----
    const float* ub = u + b * 24;
    float T[3][4];
#pragma unroll
    for (int i = 0; i < 3; ++i) {
        float v[8];
#pragma unroll
        for (int n = 0; n < 8; ++n) {
            const float sg = (n & (4 >> i)) ? 1.f : -1.f;
            v[n] = fmaf(sg * 0.025f, ub[n * 3 + i], sg * 0.1f);  // sg*(0.8+0.2u)/8
        }
        const float a0 = v[0] + v[1], a1 = v[2] + v[3];
        const float a2 = v[4] + v[5], a3 = v[6] + v[7];
        const float d0 = v[1] - v[0], d1 = v[3] - v[2];
        const float d2 = v[5] - v[4], d3 = v[7] - v[6];
        const float A01 = a0 + a1, A23 = a2 + a3;
        T[i][0] = A23 - A01;
        T[i][1] = (a1 - a0) + (a3 - a2);
        T[i][2] = (d0 + d1) + (d2 + d3);
        T[i][3] = A01 + A23;
    }
    const float t00 = T[0][0], t01 = T[0][1], t02 = T[0][2], t03 = T[0][3];
    const float t10 = T[1][0], t11 = T[1][1], t12 = T[1][2], t13 = T[1][3];
    const float t20 = T[2][0], t21 = T[2][1], t22 = T[2][2], t23 = T[2][3];

    const int d0i = dblk << 3, w0i = wblk << 5;
    const int h0w = (hblk << 2) + (wid << 1);        // per-WAVE h base (2 rows)
    const float inv = 2.0f / 127.0f;
    const float x0 = -1.f + d0i * inv, y0 = -1.f + h0w * inv, z0 = -1.f + w0i * inv;
    // pixel coords at wave-tile origin; per-index pixel delta == t
    const float P0 = (t00 * x0 + t01 * y0 + t02 * z0 + t03 + 1.f) * 63.5f;
    const float P1 = (t10 * x0 + t11 * y0 + t12 * z0 + t13 + 1.f) * 63.5f;
    const float P2 = (t20 * x0 + t21 * y0 + t22 * z0 + t23 + 1.f) * 63.5f;

    // window minima via corner extremes (kd<=7, dh<=1, kw<=31); maxima not
    // needed: fixed-size clamped windows cover all taps by the span proof.
    const float mn0 = P0 + fminf(0.f,7.f*t00)+fminf(0.f,t01)+fminf(0.f,31.f*t02);
    const float mn1 = P1 + fminf(0.f,7.f*t10)+fminf(0.f,t11)+fminf(0.f,31.f*t12);
    const float mn2 = P2 + fminf(0.f,7.f*t20)+fminf(0.f,t21)+fminf(0.f,31.f*t22);
    const int i0mn = (int)floorf(mn0);
    const int i1mn = (int)floorf(mn1);
    const int i2mn = (int)floorf(mn2);

    const int wsu  = (i2mn - 1) & ~3;               // 4-aligned (works for <0)
    const int d_lo = min(max(i0mn, 0), NS - SD);    // clamp window into image
    const int h_lo = min(max(i1mn, 0), NS - SHW);
    const int ws   = min(max(wsu, 0), NS - ROW_W);
    // interior <=> window unclamped (then taps are provably inside it & image)
    const int allin = __builtin_amdgcn_readfirstlane(
        (i0mn >= 0 && i0mn <= NS - SD && i1mn >= 0 && i1mn <= NS - SHW &&
         wsu  >= 0 && wsu  <= NS - ROW_W) ? 1 : 0);

    const float Pl0 = P0 - (float)d_lo;     // local-window coordinates
    const float Pl1 = P1 - (float)h_lo;
    const float Pl2 = P2 - (float)ws;

    // ---- stage: 15 unconditional lane-linear 16B loads, flat over the slice.
    // lane float index = 256*j + 4*lane -> (plane p, rem); global addr =
    // base + p*16384 + rem + (rem/40)*88  (since r*128+c = rem + r*88).
    // p clamped to 12 for the pad tail (valid dup reads, never consumed). ----
    float* wslab = slab + wid * WSTRIDE;
    {
        const float* gwb = img + (size_t)b * VOX
                         + (d_lo * NS + h_lo) * NS + ws;
        int p = 0, rem = lane << 2;
#pragma unroll
        for (int j = 0; j < NLOAD; ++j) {
            const int pp = min(p, SD - 1);
            const int r  = (rem * 205) >> 13;            // rem/40, rem<280
            const float* g = gwb + pp * (NS * NS) + rem + r * 88;
            __builtin_amdgcn_global_load_lds(
                (gconst_t*)g, (lds_t*)(wslab + j * 256), 16, 0, 0);
            rem += 256;
            if (rem >= PLANE) { rem -= PLANE; ++p; }
        }
    }

    // ---- compute: NO barrier; wave-local counted vmcnt ladder (interior) ----
    const int wl = lane & 31, hw = lane >> 5;
    float ql0 = Pl0 + hw * t01 + wl * t02;
    float ql1 = Pl1 + hw * t11 + wl * t12;
    float ql2 = Pl2 + hw * t21 + wl * t22;

    float res[8];

#define ITAP(k)                                                               \
    {                                                                         \
        const float f0 = floorf(ql0), f1 = floorf(ql1), f2 = floorf(ql2);     \
        const float r0 = ql0 - f0, r1 = ql1 - f1, r2 = ql2 - f2;              \
        const int base = (int)fmaf(f0, 280.f, fmaf(f1, 40.f, f2));            \
        const float a00 = wslab[base],       b00 = wslab[base + 1];           \
        const float a01 = wslab[base + 40],  b01 = wslab[base + 41];          \
        const float a10 = wslab[base + 280], b10 = wslab[base + 281];         \
        const float a11 = wslab[base + 320], b11 = wslab[base + 321];         \
        const float e0 = fmaf(r2, b00 - a00, a00);                            \
        const float e1 = fmaf(r2, b01 - a01, a01);                            \
        const float e2 = fmaf(r2, b10 - a10, a10);                            \
        const float e3 = fmaf(r2, b11 - a11, a11);                            \
        const float c0 = fmaf(r1, e1 - e0, e0);                               \
        const float c1 = fmaf(r1, e3 - e2, e2);                               \
        res[k] = fmaf(r0, c1 - c0, c0);                                       \
        ql0 += t00; ql1 += t10; ql2 += t20;                                   \
    }

    if (allin) {
        // k needs planes <= 6+k -> wait loads {7,8,9,10,11,13,14,15}
        asm volatile("s_waitcnt vmcnt(8)" ::: "memory"); ITAP(0)
        asm volatile("s_waitcnt vmcnt(7)" ::: "memory"); ITAP(1)
        asm volatile("s_waitcnt vmcnt(6)" ::: "memory"); ITAP(2)
        asm volatile("s_waitcnt vmcnt(5)" ::: "memory"); ITAP(3)
        asm volatile("s_waitcnt vmcnt(4)" ::: "memory"); ITAP(4)
        asm volatile("s_waitcnt vmcnt(2)" ::: "memory"); ITAP(5)
        asm volatile("s_waitcnt vmcnt(1)" ::: "memory"); ITAP(6)
        asm volatile("s_waitcnt vmcnt(0)" ::: "memory"); ITAP(7)
    } else {
        // boundary (~55% of waves): single wave-local drain, then masked-
        // weight clamped taps (R0-proven semantics; window covers all valid
        // taps; clamped/garbage values carry weight 0; pair-read +1 stays in
        // the 3840-float padded slice).
        asm volatile("s_waitcnt vmcnt(0)" ::: "memory");
#pragma unroll
        for (int k = 0; k < 8; ++k) {
            const float f0 = floorf(ql0), f1 = floorf(ql1), f2 = floorf(ql2);
            const float r0 = ql0 - f0, r1 = ql1 - f1, r2 = ql2 - f2;
            const int i0 = (int)f0, i1 = (int)f1, i2 = (int)f2;  // local

            const float wd0 = ((unsigned)(i0 + d_lo)     < NS) ? 1.f - r0 : 0.f;
            const float wd1 = ((unsigned)(i0 + d_lo + 1) < NS) ? r0       : 0.f;
            const float wh0 = ((unsigned)(i1 + h_lo)     < NS) ? 1.f - r1 : 0.f;
            const float wh1 = ((unsigned)(i1 + h_lo + 1) < NS) ? r1       : 0.f;
            const float ww0 = ((unsigned)(i2 + ws)       < NS) ? 1.f - r2 : 0.f;
            const float ww1 = ((unsigned)(i2 + ws + 1)   < NS) ? r2       : 0.f;

            const int dI0 = min(max(i0,     0), SD  - 1);
            const int dI1 = min(max(i0 + 1, 0), SD  - 1);
            const int hI0 = min(max(i1,     0), SHW - 1);
            const int hI1 = min(max(i1 + 1, 0), SHW - 1);
            const int j0  = min(max(i2,     0), ROW_W - 1);
            const int j1  = min(max(i2 + 1, 0), ROW_W - 1);
            const bool same = (j1 == j0);

            float acc = 0.f;
            {
                const int bb = dI0 * PLANE + hI0 * ROW_W + j0;
                const float a = wslab[bb], bv = wslab[bb + 1];
                const float rt = same ? a : bv;
                acc = fmaf(fmaf(a, ww0, rt * ww1), wd0 * wh0, acc);
            }
            {
                const int bb = dI0 * PLANE + hI1 * ROW_W + j0;
                const float a = wslab[bb], bv = wslab[bb + 1];
                const float rt = same ? a : bv;
                acc = fmaf(fmaf(a, ww0, rt * ww1), wd0 * wh1, acc);
            }
            {
                const int bb = dI1 * PLANE + hI0 * ROW_W + j0;
                const float a = wslab[bb], bv = wslab[bb + 1];
                const float rt = same ? a : bv;
                acc = fmaf(fmaf(a, ww0, rt * ww1), wd1 * wh0, acc);
            }
            {
                const int bb = dI1 * PLANE + hI1 * ROW_W + j0;
                const float a = wslab[bb], bv = wslab[bb + 1];
                const float rt = same ? a : bv;
                acc = fmaf(fmaf(a, ww0, rt * ww1), wd1 * wh1, acc);
            }
            res[k] = acc;

            ql0 += t00; ql1 += t10; ql2 += t20;
        }
    }
#undef ITAP

    // stores: wave = 2 h-rows x 32 consecutive w -> coalesced 128B segments
    size_t ob = (((size_t)(b * NS + d0i) * NS + (h0w + hw)) * NS) + w0i + wl;
#pragma unroll
    for (int k = 0; k < 8; ++k)
        out[ob + (size_t)k * NS * NS] = res[k];
}

extern "C" void kernel_launch(void* const* d_in, const int* in_sizes, int n_in,
                              void* d_out, int out_size, void* d_ws, size_t ws_size,
                              hipStream_t stream) {
    const float* img = (const float*)d_in[0];   // [8,128,128,128,1] fp32
    const float* u   = (const float*)d_in[1];   // [8,8,3] fp32
    float* out = (float*)d_out;

    int blocks = NB * 16 * 32 * 4;              // 16,384 (b=xcd x 16d x 32h x 4w)
    warp_resample_kernel<<<blocks, 128, 0, stream>>>(img, u, out);
}